// Round 1
// baseline (227.524 us; speedup 1.0000x reference)
//
#include <hip/hip_runtime.h>
#include <hip/hip_bf16.h>
#include <math.h>

#define NT 1200
#define NB 16384
#define NY 8
#define NGROUPS (NT * NB)            // 19,660,800 groups of 8 contiguous floats
#define W_LOW  0.2f
#define W_HIGH 1.75f

// Stage 1: grid-stride over 8-element groups; accumulate w^2*(o-t)^2 per channel.
__global__ __launch_bounds__(256) void rmse_partial_kernel(
    const float* __restrict__ outp, const float* __restrict__ tgtp,
    float* __restrict__ ws)
{
    float acc[NY];
#pragma unroll
    for (int c = 0; c < NY; ++c) acc[c] = 0.0f;

    const int stride = gridDim.x * blockDim.x;
    const float4* __restrict__ o4 = reinterpret_cast<const float4*>(outp);
    const float4* __restrict__ t4 = reinterpret_cast<const float4*>(tgtp);

    for (int g = blockIdx.x * blockDim.x + threadIdx.x; g < NGROUPS; g += stride) {
        const int t   = g >> 14;          // g / NB
        const int mon = t % 12;
        const float w  = (mon >= 6 && mon <= 9) ? W_HIGH : W_LOW;
        const float w2 = w * w;

        const int base = g << 1;          // float4 index
        float4 a0 = o4[base];
        float4 a1 = o4[base + 1];
        float4 b0 = t4[base];
        float4 b1 = t4[base + 1];

        float d;
        d = a0.x - b0.x; acc[0] += w2 * d * d;
        d = a0.y - b0.y; acc[1] += w2 * d * d;
        d = a0.z - b0.z; acc[2] += w2 * d * d;
        d = a0.w - b0.w; acc[3] += w2 * d * d;
        d = a1.x - b1.x; acc[4] += w2 * d * d;
        d = a1.y - b1.y; acc[5] += w2 * d * d;
        d = a1.z - b1.z; acc[6] += w2 * d * d;
        d = a1.w - b1.w; acc[7] += w2 * d * d;
    }

    // Wave (64-lane) reduction per channel.
#pragma unroll
    for (int c = 0; c < NY; ++c) {
        float v = acc[c];
#pragma unroll
        for (int off = 32; off > 0; off >>= 1)
            v += __shfl_down(v, off, 64);
        acc[c] = v;
    }

    __shared__ float sh[4][NY];           // 256 threads = 4 waves
    const int wave = threadIdx.x >> 6;
    const int lane = threadIdx.x & 63;
    if (lane == 0) {
#pragma unroll
        for (int c = 0; c < NY; ++c) sh[wave][c] = acc[c];
    }
    __syncthreads();

    if (threadIdx.x < NY) {
        const int c = threadIdx.x;
        float s = sh[0][c] + sh[1][c] + sh[2][c] + sh[3][c];
        atomicAdd(&ws[c], s);             // device-scope by default on CDNA
    }
}

// Stage 2: finalize — sum over channels of sqrt(mean).
__global__ void rmse_final_kernel(const float* __restrict__ ws, float* __restrict__ out)
{
    if (threadIdx.x == 0 && blockIdx.x == 0) {
        const float inv_n = 1.0f / (float)NGROUPS;   // mean over NT*NB per channel
        float s = 0.0f;
#pragma unroll
        for (int c = 0; c < NY; ++c)
            s += sqrtf(ws[c] * inv_n);
        out[0] = s;
    }
}

extern "C" void kernel_launch(void* const* d_in, const int* in_sizes, int n_in,
                              void* d_out, int out_size, void* d_ws, size_t ws_size,
                              hipStream_t stream) {
    const float* outp = (const float*)d_in[0];
    const float* tgtp = (const float*)d_in[1];
    float* ws  = (float*)d_ws;
    float* out = (float*)d_out;

    // Harness poisons d_ws once and never re-poisons between replays:
    // zero our 8 accumulators every call.
    hipMemsetAsync(ws, 0, NY * sizeof(float), stream);

    const int block = 256;
    const int grid  = 2048;               // ~8 blocks/CU, grid-stride covers the rest
    rmse_partial_kernel<<<grid, block, 0, stream>>>(outp, tgtp, ws);
    rmse_final_kernel<<<1, 64, 0, stream>>>(ws, out);
}